// Round 1
// baseline (111.825 us; speedup 1.0000x reference)
//
#include <hip/hip_runtime.h>

#define B_DIM 256
#define E_DIM 8192
#define C_DIM 19

// d_ws float layout:
//  [0  .. 18]  cap_raw  (count of e_true>=0.5 over E, per class)
//  [19 .. 37]  n_pos    (count of y_true>=0.5 over B, per class, as float)
//  [38 .. 56]  sum_yp   (sum of y_pred over B, per class)
//  [57 .. 75]  acc      (m2 + m3 raw accumulator, per class)

__global__ void rocstar_prep(const float* __restrict__ y_pred,
                             const float* __restrict__ y_true,
                             const float* __restrict__ epoch_true,
                             float* __restrict__ ws) {
    const int c   = blockIdx.x;
    const int tid = threadIdx.x;
    __shared__ float red[B_DIM];

    // --- count (e_true >= 0.5) over E ---
    float cnt = 0.0f;
    for (int j = tid; j < E_DIM; j += B_DIM)
        cnt += (epoch_true[j * C_DIM + c] >= 0.5f) ? 1.0f : 0.0f;
    red[tid] = cnt;
    __syncthreads();
    for (int s = B_DIM / 2; s > 0; s >>= 1) {
        if (tid < s) red[tid] += red[tid + s];
        __syncthreads();
    }
    if (tid == 0) ws[0 * C_DIM + c] = red[0];
    __syncthreads();

    // --- n_pos over B (B == blockDim.x == 256) ---
    const float ypv = y_pred[tid * C_DIM + c];
    red[tid] = (y_true[tid * C_DIM + c] >= 0.5f) ? 1.0f : 0.0f;
    __syncthreads();
    for (int s = B_DIM / 2; s > 0; s >>= 1) {
        if (tid < s) red[tid] += red[tid + s];
        __syncthreads();
    }
    if (tid == 0) ws[1 * C_DIM + c] = red[0];
    __syncthreads();

    // --- sum_yp over B ---
    red[tid] = ypv;
    __syncthreads();
    for (int s = B_DIM / 2; s > 0; s >>= 1) {
        if (tid < s) red[tid] += red[tid + s];
        __syncthreads();
    }
    if (tid == 0) {
        ws[2 * C_DIM + c] = red[0];
        ws[3 * C_DIM + c] = 0.0f;   // zero the pair accumulator (ws is poisoned)
    }
}

__global__ void rocstar_pairs(const float* __restrict__ y_pred,
                              const float* __restrict__ y_true,
                              const float* __restrict__ epoch_pred,
                              const float* __restrict__ epoch_true,
                              const float* __restrict__ gamma,
                              const float* __restrict__ rand_pos,
                              const float* __restrict__ rand_neg,
                              float* __restrict__ ws) {
    const int c   = blockIdx.y;
    const int tid = threadIdx.x;
    const int j   = blockIdx.x * B_DIM + tid;

    __shared__ float s_yp[B_DIM];
    __shared__ float s_pm[B_DIM];   // 1.0 if y_true>=0.5 else 0.0
    __shared__ float red[B_DIM];

    s_yp[tid] = y_pred[tid * C_DIM + c];
    s_pm[tid] = (y_true[tid * C_DIM + c] >= 0.5f) ? 1.0f : 0.0f;
    __syncthreads();

    const float cap = fmaxf(ws[0 * C_DIM + c], 1.0f);
    const float p   = 1000.0f / cap;          // MAX_POS / cap_pos (f32, matches ref)
    const float g   = gamma[c];

    const float ep  = epoch_pred[j * C_DIM + c];
    const bool  et  = epoch_true[j * C_DIM + c] >= 0.5f;
    const float rp  = rand_pos[j * C_DIM + c];
    const float rn  = rand_neg[j * C_DIM + c];

    // faithful to the reference "bug": both masks use p derived from cap_pos
    const float w2 = (!et && (rn < p)) ? 1.0f : 0.0f;  // j is a subsampled epoch NEGATIVE
    const float w3 = ( et && (rp < p)) ? 1.0f : 0.0f;  // j is a subsampled epoch POSITIVE

    float acc = 0.0f;
    if (w2 != 0.0f || w3 != 0.0f) {
        #pragma unroll 4
        for (int i = 0; i < B_DIM; ++i) {
            const float ypi = s_yp[i];   // broadcast across the wave — conflict-free
            const float pm  = s_pm[i];
            float d2 = ep - ypi + g;     // (e_pred - yp) + g, same assoc as ref
            d2 = fmaxf(d2, 0.0f);
            float d3 = ypi - ep + g;     // (yp - e_pred) + g
            d3 = fmaxf(d3, 0.0f);
            acc += d2 * d2 * (pm * w2) + d3 * d3 * ((1.0f - pm) * w3);
        }
    }

    red[tid] = acc;
    __syncthreads();
    for (int s = B_DIM / 2; s > 0; s >>= 1) {
        if (tid < s) red[tid] += red[tid + s];
        __syncthreads();
    }
    if (tid == 0) atomicAdd(&ws[3 * C_DIM + c], red[0]);
}

__global__ void rocstar_final(const float* __restrict__ ws,
                              float* __restrict__ out) {
    if (threadIdx.x == 0 && blockIdx.x == 0) {
        float total = 0.0f;
        for (int c = 0; c < C_DIM; ++c) {
            const float npos = ws[1 * C_DIM + c];
            float res;
            if (npos == 0.0f || npos == (float)B_DIM) {
                res = ws[2 * C_DIM + c] * 1e-8f;       // degenerate: sum(yp)*1e-8
            } else {
                res = ws[3 * C_DIM + c] / 1000.0f;     // m2/MAX_POS + m3/MAX_NEG
                if (isnan(res)) res = 0.0f;
            }
            total += res;
        }
        out[0] = total / (float)C_DIM;                 // mean over classes
    }
}

extern "C" void kernel_launch(void* const* d_in, const int* in_sizes, int n_in,
                              void* d_out, int out_size, void* d_ws, size_t ws_size,
                              hipStream_t stream) {
    const float* y_pred     = (const float*)d_in[0];
    const float* y_true     = (const float*)d_in[1];
    const float* epoch_pred = (const float*)d_in[2];
    const float* epoch_true = (const float*)d_in[3];
    const float* gamma      = (const float*)d_in[4];
    const float* rand_pos   = (const float*)d_in[5];
    const float* rand_neg   = (const float*)d_in[6];
    float*       out        = (float*)d_out;
    float*       ws         = (float*)d_ws;

    rocstar_prep<<<C_DIM, B_DIM, 0, stream>>>(y_pred, y_true, epoch_true, ws);

    dim3 grid(E_DIM / B_DIM, C_DIM);   // 32 x 19 blocks
    rocstar_pairs<<<grid, B_DIM, 0, stream>>>(y_pred, y_true, epoch_pred, epoch_true,
                                              gamma, rand_pos, rand_neg, ws);

    rocstar_final<<<1, 64, 0, stream>>>(ws, out);
}

// Round 2
// 83.466 us; speedup vs baseline: 1.3398x; 1.3398x over previous
//
#include <hip/hip_runtime.h>

#define B_DIM 256
#define E_DIM 8192
#define C_DIM 19
#define XBLK  32   // E_DIM / B_DIM

// ws layout (floats), all plain writes (no atomics, no pre-zero needed):
//  [0    .. 607 ]  capP[c*32+x]  partial count of (e_true>=0.5) over j-slice
//  [608  .. 626 ]  n_pos[c]      count of (y_true>=0.5) over B
//  [627  .. 645 ]  sum_yp[c]     sum of y_pred over B
//  [646  .. 1253]  mP[c*32+x]    partial (m2+m3) raw accumulator
#define WS_CAP  0
#define WS_NPOS 608
#define WS_SYP  627
#define WS_M    646

// Block-wide sum (256 threads = 4 waves). Result valid on tid==0 only.
__device__ __forceinline__ float block_sum(float v, int tid, float* red4) {
    #pragma unroll
    for (int off = 32; off > 0; off >>= 1) v += __shfl_down(v, off, 64);
    if ((tid & 63) == 0) red4[tid >> 6] = v;
    __syncthreads();
    float r = 0.0f;
    if (tid == 0) r = red4[0] + red4[1] + red4[2] + red4[3];
    __syncthreads();   // allow safe reuse of red4
    return r;
}

// K1: grid (32,19) x 256. Per-class partial cap counts; block x==0 also does
// the B-reductions (n_pos, sum_yp). All written, nothing atomic.
__global__ void rocstar_k1(const float* __restrict__ y_pred,
                           const float* __restrict__ y_true,
                           const float* __restrict__ epoch_true,
                           float* __restrict__ ws) {
    const int c   = blockIdx.y;
    const int x   = blockIdx.x;
    const int tid = threadIdx.x;
    const int j   = x * B_DIM + tid;
    __shared__ float red4[4];

    const float cnt = (epoch_true[j * C_DIM + c] >= 0.5f) ? 1.0f : 0.0f;
    const float cs  = block_sum(cnt, tid, red4);
    if (tid == 0) ws[WS_CAP + c * XBLK + x] = cs;

    if (x == 0) {
        const float ypv = y_pred[tid * C_DIM + c];
        const float ytv = (y_true[tid * C_DIM + c] >= 0.5f) ? 1.0f : 0.0f;
        const float np  = block_sum(ytv, tid, red4);
        if (tid == 0) ws[WS_NPOS + c] = np;
        const float sy  = block_sum(ypv, tid, red4);
        if (tid == 0) ws[WS_SYP + c] = sy;
    }
}

// K2: grid (32,19) x 256. Pairwise hinge^2 sums. yp/pos-mask staged in LDS as
// float2 (one broadcast ds_read_b64 per inner iter). Partial per block, written.
__global__ void rocstar_k2(const float* __restrict__ y_pred,
                           const float* __restrict__ y_true,
                           const float* __restrict__ epoch_pred,
                           const float* __restrict__ epoch_true,
                           const float* __restrict__ gamma,
                           const float* __restrict__ rand_pos,
                           const float* __restrict__ rand_neg,
                           float* __restrict__ ws) {
    const int c   = blockIdx.y;
    const int x   = blockIdx.x;
    const int tid = threadIdx.x;
    const int j   = x * B_DIM + tid;

    __shared__ float2 s_yp[B_DIM];
    __shared__ float  red4[4];

    s_yp[tid] = make_float2(y_pred[tid * C_DIM + c],
                            (y_true[tid * C_DIM + c] >= 0.5f) ? 1.0f : 0.0f);

    // cap = sum of the 32 partials (uniform-address loads, L2-hot)
    float cap = 0.0f;
    #pragma unroll
    for (int t = 0; t < XBLK; ++t) cap += ws[WS_CAP + c * XBLK + t];
    cap = fmaxf(cap, 1.0f);
    const float p = 1000.0f / cap;          // MAX_POS / cap_pos (f32, as ref)
    const float g = gamma[c];

    const float ep = epoch_pred[j * C_DIM + c];
    const bool  et = epoch_true[j * C_DIM + c] >= 0.5f;
    const float rp = rand_pos[j * C_DIM + c];
    const float rn = rand_neg[j * C_DIM + c];

    // faithful to the reference "bug": both masks use p from cap_pos
    const float w2 = (!et && (rn < p)) ? 1.0f : 0.0f;  // subsampled epoch NEG
    const float w3 = ( et && (rp < p)) ? 1.0f : 0.0f;  // subsampled epoch POS

    __syncthreads();

    float acc2 = 0.0f, acc3 = 0.0f;
    if (w2 != 0.0f || w3 != 0.0f) {
        const float epg2 = ep + g;   // d2 = (ep - yp) + g  ~= (ep+g) - yp
        const float epg3 = ep - g;   // d3 = (yp - ep) + g  ~= yp - (ep-g)
        #pragma unroll 8
        for (int i = 0; i < B_DIM; ++i) {
            const float2 v = s_yp[i];             // broadcast — conflict-free
            float d2 = fmaxf(epg2 - v.x, 0.0f);
            float d3 = fmaxf(v.x - epg3, 0.0f);
            acc2 = fmaf(d2 * d2, v.y, acc2);          // vs pos_m rows
            acc3 = fmaf(d3 * d3, 1.0f - v.y, acc3);   // vs neg_m rows
        }
    }
    const float acc = w2 * acc2 + w3 * acc3;

    const float bs = block_sum(acc, tid, red4);
    if (tid == 0) ws[WS_M + c * XBLK + x] = bs;
}

// K3: one block. Thread c<19 folds its class's 32 partials + degenerate logic;
// single-wave shuffle reduce over classes.
__global__ void rocstar_k3(const float* __restrict__ ws,
                           float* __restrict__ out) {
    const int tid = threadIdx.x;
    float r = 0.0f;
    if (tid < C_DIM) {
        float m = 0.0f;
        #pragma unroll
        for (int t = 0; t < XBLK; ++t) m += ws[WS_M + tid * XBLK + t];
        float v = m / 1000.0f;                  // m2/MAX_POS + m3/MAX_NEG
        if (isnan(v)) v = 0.0f;
        const float npos = ws[WS_NPOS + tid];
        r = (npos == 0.0f || npos == (float)B_DIM)
                ? ws[WS_SYP + tid] * 1e-8f      // degenerate: sum(yp)*1e-8
                : v;
    }
    #pragma unroll
    for (int off = 16; off > 0; off >>= 1) r += __shfl_down(r, off, 64);
    if (tid == 0) out[0] = r / (float)C_DIM;    // mean over classes
}

extern "C" void kernel_launch(void* const* d_in, const int* in_sizes, int n_in,
                              void* d_out, int out_size, void* d_ws, size_t ws_size,
                              hipStream_t stream) {
    const float* y_pred     = (const float*)d_in[0];
    const float* y_true     = (const float*)d_in[1];
    const float* epoch_pred = (const float*)d_in[2];
    const float* epoch_true = (const float*)d_in[3];
    const float* gamma      = (const float*)d_in[4];
    const float* rand_pos   = (const float*)d_in[5];
    const float* rand_neg   = (const float*)d_in[6];
    float*       out        = (float*)d_out;
    float*       ws         = (float*)d_ws;

    const dim3 grid(XBLK, C_DIM);   // 32 x 19
    rocstar_k1<<<grid, B_DIM, 0, stream>>>(y_pred, y_true, epoch_true, ws);
    rocstar_k2<<<grid, B_DIM, 0, stream>>>(y_pred, y_true, epoch_pred, epoch_true,
                                           gamma, rand_pos, rand_neg, ws);
    rocstar_k3<<<1, 64, 0, stream>>>(ws, out);
}